// Round 9
// baseline (28.688 us; speedup 1.0000x reference)
//
#include <hip/hip_runtime.h>

// out[i] = MLP(emb_user[uid[i]]) + MLP(emb_movie[mid[i]])
// MLP: relu(x@W1+b1) -> relu(@W2+b2) -> @W3+b3.  Single kernel, 32x32x16
// bf16 MFMA, fp32 acc, sigma-permuted W1 (register-only layer1->layer2
// handoff, validated rounds 4-8).
//
// Round-9: SPLIT-TABLE SOFTWARE PIPELINE.  User and movie MLPs only meet at
// the final scalar add, so run them as two sequential passes per wave:
//   idx -> weight loads (oldest in vmcnt) -> user gathers -> stage weights
//   (waits weights only) -> issue MOVIE gathers -> convert user frags ->
//   barrier -> USER pass (movie gathers fly underneath, ~4us of compute)
//   -> convert movie frags (already landed) -> MOVIE pass -> combine.
// Movie raw gathers ride in 64 VGPRs through the user pass.  No NT hints
// (movie rows have ~27% reuse; let L2/L3 keep them).  No in-loop restaging.
//
// LDS: w1f 32KB + w2f 64KB = 96KB, fragment-order (1KB frag @ base+lane*16,
// conflict-free).  512 thr = 8 waves x 32 samples.  Grid 256 = 1 block/CU,
// 2 waves/SIMD.  One barrier total.

typedef __attribute__((ext_vector_type(8))) short bf16x8;
typedef __attribute__((ext_vector_type(16))) float f32x16;

__device__ __forceinline__ unsigned int cvt_pk(float lo, float hi) {
  unsigned int r;
  asm("v_cvt_pk_bf16_f32 %0, %1, %2" : "=v"(r) : "v"(lo), "v"(hi));
  return r;  // bf16(lo) in [15:0], bf16(hi) in [31:16], RNE
}

__global__ __launch_bounds__(512, 2) void movielens_mlp(
    const int* __restrict__ uids, const int* __restrict__ mids,
    const float* __restrict__ EU, const float* __restrict__ EM,
    const float* __restrict__ W1, const float* __restrict__ B1,
    const float* __restrict__ W2, const float* __restrict__ B2,
    const float* __restrict__ W3, const float* __restrict__ B3,
    float* __restrict__ out) {
  __shared__ __align__(16) unsigned short w1f[32 * 512];  // 32 KB
  __shared__ __align__(16) unsigned short w2f[64 * 512];  // 64 KB

  const int tid = threadIdx.x;
  const int lane = tid & 63, wv = tid >> 6;
  const int m32 = lane & 31, H = lane >> 5;
  const int sbase = blockIdx.x * 256 + wv * 32;
  const int sid = sbase + m32;

  // ---- idx loads (head of both gather chains) ----
  const int uid = uids[sid];
  const int mid = mids[sid];

  // staging unit geometry (validated r8)
  const int cq = tid & 7, bb = (tid >> 3) & 1, hh = (tid >> 4) & 1;

  // ---- weight loads FIRST (oldest in vmcnt: staging waits only these) ----
  float4 wr[6][4];
#pragma unroll
  for (int i = 0; i < 2; ++i) {  // W1 units
    const int fi = (tid >> 5) + 16 * i;  // 0..31 = ct*4+kk
    const int ct = fi >> 2, kk = fi & 3;
    const float* s = W1 + (16 * kk + 8 * hh + 4 * bb) * 256 + 32 * ct + 4 * cq;
    wr[i][0] = *(const float4*)(s);
    wr[i][1] = *(const float4*)(s + 256);
    wr[i][2] = *(const float4*)(s + 512);
    wr[i][3] = *(const float4*)(s + 768);
  }
#pragma unroll
  for (int i = 2; i < 6; ++i) {  // W2 units
    const int f2 = (tid >> 5) + 16 * (i - 2);  // 0..63 = ks*4+n2
    const int ks = f2 >> 2, n2 = f2 & 3;
    const float* s = W2 + (16 * ks + 8 * hh + 4 * bb) * 128 + 32 * n2 + 4 * cq;
    wr[i][0] = *(const float4*)(s);
    wr[i][1] = *(const float4*)(s + 128);
    wr[i][2] = *(const float4*)(s + 256);
    wr[i][3] = *(const float4*)(s + 384);
  }

  // ---- user gathers (needed first) ----
  const float* rowU = EU + (size_t)uid * 64;
  float4 xu[4][2];
#pragma unroll
  for (int kk = 0; kk < 4; ++kk) {
    xu[kk][0] = *(const float4*)(rowU + 16 * kk + 8 * H);
    xu[kk][1] = *(const float4*)(rowU + 16 * kk + 8 * H + 4);
  }

  // ---- stage W1 (sigma-permuted) + W2 (waits weight loads only) ----
  const int w1slot0 = 32 * hh + 16 * (cq >> 2) + 8 * (cq & 1) + 4 * ((cq >> 1) & 1);
#pragma unroll
  for (int i = 0; i < 2; ++i) {
    const int fi = (tid >> 5) + 16 * i;
    const float c0[4] = {wr[i][0].x, wr[i][0].y, wr[i][0].z, wr[i][0].w};
    const float c1[4] = {wr[i][1].x, wr[i][1].y, wr[i][1].z, wr[i][1].w};
    const float c2[4] = {wr[i][2].x, wr[i][2].y, wr[i][2].z, wr[i][2].w};
    const float c3[4] = {wr[i][3].x, wr[i][3].y, wr[i][3].z, wr[i][3].w};
#pragma unroll
    for (int s = 0; s < 4; ++s) {
      uint2 pk;
      pk.x = cvt_pk(c0[s], c1[s]);
      pk.y = cvt_pk(c2[s], c3[s]);
      *(uint2*)&w1f[fi * 512 + (w1slot0 + s) * 8 + 4 * bb] = pk;
    }
  }
#pragma unroll
  for (int i = 2; i < 6; ++i) {
    const int f2 = (tid >> 5) + 16 * (i - 2);
    const int slot0 = 32 * hh + 4 * cq;
    const float c0[4] = {wr[i][0].x, wr[i][0].y, wr[i][0].z, wr[i][0].w};
    const float c1[4] = {wr[i][1].x, wr[i][1].y, wr[i][1].z, wr[i][1].w};
    const float c2[4] = {wr[i][2].x, wr[i][2].y, wr[i][2].z, wr[i][2].w};
    const float c3[4] = {wr[i][3].x, wr[i][3].y, wr[i][3].z, wr[i][3].w};
#pragma unroll
    for (int s = 0; s < 4; ++s) {
      uint2 pk;
      pk.x = cvt_pk(c0[s], c1[s]);
      pk.y = cvt_pk(c2[s], c3[s]);
      *(uint2*)&w2f[f2 * 512 + (slot0 + s) * 8 + 4 * bb] = pk;
    }
  }

  // ---- issue MOVIE gathers now: they fly during convert+barrier+user pass ----
  const float* rowM = EM + (size_t)mid * 64;
  float4 xm[4][2];
#pragma unroll
  for (int kk = 0; kk < 4; ++kk) {
    xm[kk][0] = *(const float4*)(rowM + 16 * kk + 8 * H);
    xm[kk][1] = *(const float4*)(rowM + 16 * kk + 8 * H + 4);
  }

  // ---- convert user gathers to B-frags (drains user vmcnt, not movie) ----
  bf16x8 xfu[4];
#pragma unroll
  for (int kk = 0; kk < 4; ++kk) {
    const float4 a = xu[kk][0], b = xu[kk][1];
    uint4 w;
    w.x = cvt_pk(a.x, a.y);
    w.y = cvt_pk(a.z, a.w);
    w.z = cvt_pk(b.x, b.y);
    w.w = cvt_pk(b.z, b.w);
    xfu[kk] = __builtin_bit_cast(bf16x8, w);
  }
  __syncthreads();

  // ---- one full MLP pass (layers 1-3) for one table's 32 samples ----
  auto run_pass = [&](const bf16x8 xf[4]) -> float {
    f32x16 acc2[4];
#pragma unroll
    for (int n2 = 0; n2 < 4; ++n2)
#pragma unroll
      for (int rq = 0; rq < 4; ++rq) {
        const float4 bq = *(const float4*)(B2 + 32 * n2 + 8 * rq + 4 * H);
        acc2[n2][4 * rq + 0] = bq.x;
        acc2[n2][4 * rq + 1] = bq.y;
        acc2[n2][4 * rq + 2] = bq.z;
        acc2[n2][4 * rq + 3] = bq.w;
      }
    bf16x8 a1[4];
#pragma unroll
    for (int kk = 0; kk < 4; ++kk)
      a1[kk] = *(const bf16x8*)&w1f[kk * 512 + lane * 8];

#pragma unroll
    for (int ct = 0; ct < 8; ++ct) {
      const float4 q0 = *(const float4*)(B1 + 32 * ct + 8 * H);
      const float4 q1 = *(const float4*)(B1 + 32 * ct + 8 * H + 4);
      const float4 q2 = *(const float4*)(B1 + 32 * ct + 8 * H + 16);
      const float4 q3 = *(const float4*)(B1 + 32 * ct + 8 * H + 20);
      f32x16 acc1;
      acc1[0] = q0.x;  acc1[1] = q0.y;  acc1[2] = q0.z;  acc1[3] = q0.w;
      acc1[4] = q1.x;  acc1[5] = q1.y;  acc1[6] = q1.z;  acc1[7] = q1.w;
      acc1[8] = q2.x;  acc1[9] = q2.y;  acc1[10] = q2.z; acc1[11] = q2.w;
      acc1[12] = q3.x; acc1[13] = q3.y; acc1[14] = q3.z; acc1[15] = q3.w;
#pragma unroll
      for (int kk = 0; kk < 4; ++kk)
        acc1 = __builtin_amdgcn_mfma_f32_32x32x16_bf16(a1[kk], xf[kk], acc1, 0, 0, 0);

      uint4 lo, hi;
      lo.x = cvt_pk(fmaxf(acc1[0], 0.f), fmaxf(acc1[1], 0.f));
      lo.y = cvt_pk(fmaxf(acc1[2], 0.f), fmaxf(acc1[3], 0.f));
      lo.z = cvt_pk(fmaxf(acc1[4], 0.f), fmaxf(acc1[5], 0.f));
      lo.w = cvt_pk(fmaxf(acc1[6], 0.f), fmaxf(acc1[7], 0.f));
      hi.x = cvt_pk(fmaxf(acc1[8], 0.f), fmaxf(acc1[9], 0.f));
      hi.y = cvt_pk(fmaxf(acc1[10], 0.f), fmaxf(acc1[11], 0.f));
      hi.z = cvt_pk(fmaxf(acc1[12], 0.f), fmaxf(acc1[13], 0.f));
      hi.w = cvt_pk(fmaxf(acc1[14], 0.f), fmaxf(acc1[15], 0.f));

      if (ct < 7) {  // prefetch next chunk's W1 frags under layer-2 MFMAs
#pragma unroll
        for (int kk = 0; kk < 4; ++kk)
          a1[kk] = *(const bf16x8*)&w1f[((ct + 1) * 4 + kk) * 512 + lane * 8];
      }

#pragma unroll
      for (int q = 0; q < 4; ++q) {
        const bf16x8 wlo = *(const bf16x8*)&w2f[(8 * ct + q) * 512 + lane * 8];
        acc2[q] = __builtin_amdgcn_mfma_f32_32x32x16_bf16(
            wlo, __builtin_bit_cast(bf16x8, lo), acc2[q], 0, 0, 0);
      }
#pragma unroll
      for (int q = 0; q < 4; ++q) {
        const bf16x8 whi = *(const bf16x8*)&w2f[(8 * ct + 4 + q) * 512 + lane * 8];
        acc2[q] = __builtin_amdgcn_mfma_f32_32x32x16_bf16(
            whi, __builtin_bit_cast(bf16x8, hi), acc2[q], 0, 0, 0);
      }
    }

    float part = 0.f;
#pragma unroll
    for (int n2 = 0; n2 < 4; ++n2)
#pragma unroll
      for (int rq = 0; rq < 4; ++rq) {
        const float4 wq = *(const float4*)(W3 + 32 * n2 + 8 * rq + 4 * H);
        part += fmaxf(acc2[n2][4 * rq + 0], 0.f) * wq.x +
                fmaxf(acc2[n2][4 * rq + 1], 0.f) * wq.y +
                fmaxf(acc2[n2][4 * rq + 2], 0.f) * wq.z +
                fmaxf(acc2[n2][4 * rq + 3], 0.f) * wq.w;
      }
    return part;
  };

  // ---- USER pass (movie gathers in flight underneath) ----
  const float part_u = run_pass(xfu);

  // ---- convert movie gathers (landed during user pass) and run pass ----
  bf16x8 xfm[4];
#pragma unroll
  for (int kk = 0; kk < 4; ++kk) {
    const float4 a = xm[kk][0], b = xm[kk][1];
    uint4 w;
    w.x = cvt_pk(a.x, a.y);
    w.y = cvt_pk(a.z, a.w);
    w.z = cvt_pk(b.x, b.y);
    w.w = cvt_pk(b.z, b.w);
    xfm[kk] = __builtin_bit_cast(bf16x8, w);
  }
  const float part_m = run_pass(xfm);

  // ---- combine across H-halves and store ----
  float part = part_u + part_m;
  part += __shfl_xor(part, 32, 64);
  if (lane < 32) out[sbase + lane] = part + 2.f * B3[0];
}

extern "C" void kernel_launch(void* const* d_in, const int* in_sizes, int n_in,
                              void* d_out, int out_size, void* d_ws, size_t ws_size,
                              hipStream_t stream) {
  const int* uids = (const int*)d_in[0];
  const int* mids = (const int*)d_in[1];
  const float* EU = (const float*)d_in[2];
  const float* EM = (const float*)d_in[3];
  const float* W1 = (const float*)d_in[4];
  const float* B1 = (const float*)d_in[5];
  const float* W2 = (const float*)d_in[6];
  const float* B2 = (const float*)d_in[7];
  const float* W3 = (const float*)d_in[8];
  const float* B3 = (const float*)d_in[9];
  float* out = (float*)d_out;

  const int B = in_sizes[0];  // 65536
  const int nblk = B / 256;   // 256 blocks x 256 samples
  hipLaunchKernelGGL(movielens_mlp, dim3(nblk), dim3(512), 0, stream,
                     uids, mids, EU, EM, W1, B1, W2, B2, W3, B3, out);
}

// Round 10
// 21.726 us; speedup vs baseline: 1.3204x; 1.3204x over previous
//
#include <hip/hip_runtime.h>

// out[i] = MLP(emb_user[uid[i]]) + MLP(emb_movie[mid[i]])
// MLP: relu(x@W1+b1) -> relu(@W2+b2) -> @W3+b3.  Single kernel, 32x32x16
// bf16 MFMA, fp32 acc, sigma-permuted W1 (register-only layer1->layer2
// handoff, validated rounds 4-9).  Compute loop is R6's (interleaved
// user/movie for ILP); staging mapping is R9's (validated).
//
// Round-10: BARRIER THAT DOESN'T DRAIN VMCNT.
//   __syncthreads() emits s_waitcnt vmcnt(0) before s_barrier, which
//   serialized the whole gather stream behind the weight staging in every
//   prior round.  The barrier only needs to order LDS writes vs LDS reads:
//     idx -> WEIGHT loads -> gathers -> stage (waits vmcnt(16): weights
//     only) -> s_waitcnt lgkmcnt(0); s_barrier   [gathers stay in flight]
//     -> convert xf (counted vmcnt drains gathers here) -> compute.
//   Gathers overlap weights+staging+barrier instead of being serial.
//
// LDS: w1f 32KB + w2f 64KB = 96KB fragment-order (1KB frag @ base+lane*16,
// conflict-free).  512 thr = 8 waves x 32 samples.  Grid 256 = 1 block/CU,
// 2 waves/SIMD.  One raw barrier total.

typedef __attribute__((ext_vector_type(8))) short bf16x8;
typedef __attribute__((ext_vector_type(16))) float f32x16;

__device__ __forceinline__ unsigned int cvt_pk(float lo, float hi) {
  unsigned int r;
  asm("v_cvt_pk_bf16_f32 %0, %1, %2" : "=v"(r) : "v"(lo), "v"(hi));
  return r;  // bf16(lo) in [15:0], bf16(hi) in [31:16], RNE
}

__global__ __launch_bounds__(512, 2) void movielens_mlp(
    const int* __restrict__ uids, const int* __restrict__ mids,
    const float* __restrict__ EU, const float* __restrict__ EM,
    const float* __restrict__ W1, const float* __restrict__ B1,
    const float* __restrict__ W2, const float* __restrict__ B2,
    const float* __restrict__ W3, const float* __restrict__ B3,
    float* __restrict__ out) {
  __shared__ __align__(16) unsigned short w1f[32 * 512];  // 32 KB
  __shared__ __align__(16) unsigned short w2f[64 * 512];  // 64 KB

  const int tid = threadIdx.x;
  const int lane = tid & 63, wv = tid >> 6;
  const int m32 = lane & 31, H = lane >> 5;
  const int sbase = blockIdx.x * 256 + wv * 32;
  const int sid = sbase + m32;

  // ---- idx loads (head of the gather chain) ----
  const int uid = uids[sid];
  const int mid = mids[sid];

  // staging unit geometry (validated r8/r9)
  const int cq = tid & 7, bb = (tid >> 3) & 1, hh = (tid >> 4) & 1;

  // ---- WEIGHT loads FIRST (oldest in vmcnt: staging waits only these) ----
  float4 wr[6][4];
#pragma unroll
  for (int i = 0; i < 2; ++i) {  // W1 units
    const int fi = (tid >> 5) + 16 * i;  // 0..31 = ct*4+kk
    const int ct = fi >> 2, kk = fi & 3;
    const float* s = W1 + (16 * kk + 8 * hh + 4 * bb) * 256 + 32 * ct + 4 * cq;
    wr[i][0] = *(const float4*)(s);
    wr[i][1] = *(const float4*)(s + 256);
    wr[i][2] = *(const float4*)(s + 512);
    wr[i][3] = *(const float4*)(s + 768);
  }
#pragma unroll
  for (int i = 2; i < 6; ++i) {  // W2 units
    const int f2 = (tid >> 5) + 16 * (i - 2);  // 0..63 = ks*4+n2
    const int ks = f2 >> 2, n2 = f2 & 3;
    const float* s = W2 + (16 * ks + 8 * hh + 4 * bb) * 128 + 32 * n2 + 4 * cq;
    wr[i][0] = *(const float4*)(s);
    wr[i][1] = *(const float4*)(s + 128);
    wr[i][2] = *(const float4*)(s + 256);
    wr[i][3] = *(const float4*)(s + 384);
  }

  // ---- gathers (younger than weights: stay in flight through staging) ----
  const float* rowU = EU + (size_t)uid * 64;
  const float* rowM = EM + (size_t)mid * 64;
  float4 xr[2][4][2];
#pragma unroll
  for (int kk = 0; kk < 4; ++kk) {
    xr[0][kk][0] = *(const float4*)(rowU + 16 * kk + 8 * H);
    xr[0][kk][1] = *(const float4*)(rowU + 16 * kk + 8 * H + 4);
    xr[1][kk][0] = *(const float4*)(rowM + 16 * kk + 8 * H);
    xr[1][kk][1] = *(const float4*)(rowM + 16 * kk + 8 * H + 4);
  }

  // ---- stage W1 (sigma-permuted) + W2 (counted wait: weights only) ----
  const int w1slot0 = 32 * hh + 16 * (cq >> 2) + 8 * (cq & 1) + 4 * ((cq >> 1) & 1);
#pragma unroll
  for (int i = 0; i < 2; ++i) {
    const int fi = (tid >> 5) + 16 * i;
    const float c0[4] = {wr[i][0].x, wr[i][0].y, wr[i][0].z, wr[i][0].w};
    const float c1[4] = {wr[i][1].x, wr[i][1].y, wr[i][1].z, wr[i][1].w};
    const float c2[4] = {wr[i][2].x, wr[i][2].y, wr[i][2].z, wr[i][2].w};
    const float c3[4] = {wr[i][3].x, wr[i][3].y, wr[i][3].z, wr[i][3].w};
#pragma unroll
    for (int s = 0; s < 4; ++s) {
      uint2 pk;
      pk.x = cvt_pk(c0[s], c1[s]);
      pk.y = cvt_pk(c2[s], c3[s]);
      *(uint2*)&w1f[fi * 512 + (w1slot0 + s) * 8 + 4 * bb] = pk;
    }
  }
#pragma unroll
  for (int i = 2; i < 6; ++i) {
    const int f2 = (tid >> 5) + 16 * (i - 2);
    const int slot0 = 32 * hh + 4 * cq;
    const float c0[4] = {wr[i][0].x, wr[i][0].y, wr[i][0].z, wr[i][0].w};
    const float c1[4] = {wr[i][1].x, wr[i][1].y, wr[i][1].z, wr[i][1].w};
    const float c2[4] = {wr[i][2].x, wr[i][2].y, wr[i][2].z, wr[i][2].w};
    const float c3[4] = {wr[i][3].x, wr[i][3].y, wr[i][3].z, wr[i][3].w};
#pragma unroll
    for (int s = 0; s < 4; ++s) {
      uint2 pk;
      pk.x = cvt_pk(c0[s], c1[s]);
      pk.y = cvt_pk(c2[s], c3[s]);
      *(uint2*)&w2f[f2 * 512 + (slot0 + s) * 8 + 4 * bb] = pk;
    }
  }

  // ---- raw barrier: order LDS writes/reads WITHOUT draining vmcnt ----
  // lgkmcnt(0) retires this wave's ds_writes; s_barrier joins waves; the
  // in-flight gathers cross the barrier untouched.
  asm volatile("s_waitcnt lgkmcnt(0)\n\ts_barrier" ::: "memory");
  __builtin_amdgcn_sched_barrier(0);

  // ---- convert gathers to layer-1 B-frags (counted vmcnt drains here) ----
  bf16x8 xf[2][4];
#pragma unroll
  for (int t = 0; t < 2; ++t)
#pragma unroll
    for (int kk = 0; kk < 4; ++kk) {
      const float4 a = xr[t][kk][0], b = xr[t][kk][1];
      uint4 w;
      w.x = cvt_pk(a.x, a.y);
      w.y = cvt_pk(a.z, a.w);
      w.z = cvt_pk(b.x, b.y);
      w.w = cvt_pk(b.z, b.w);
      xf[t][kk] = __builtin_bit_cast(bf16x8, w);
    }

  // ---- layer-2 accumulators, bias-initialized ----
  f32x16 acc2[2][4];
#pragma unroll
  for (int n2 = 0; n2 < 4; ++n2)
#pragma unroll
    for (int rq = 0; rq < 4; ++rq) {
      const float4 bq = *(const float4*)(B2 + 32 * n2 + 8 * rq + 4 * H);
      const float bv[4] = {bq.x, bq.y, bq.z, bq.w};
#pragma unroll
      for (int s = 0; s < 4; ++s) {
        acc2[0][n2][4 * rq + s] = bv[s];
        acc2[1][n2][4 * rq + s] = bv[s];
      }
    }

  bf16x8 a1[4];
#pragma unroll
  for (int kk = 0; kk < 4; ++kk)
    a1[kk] = *(const bf16x8*)&w1f[kk * 512 + lane * 8];

  // ---- main loop (R6 verbatim): 8 chunks, interleaved user/movie ----
#pragma unroll 2
  for (int ct = 0; ct < 8; ++ct) {
    const float4 q0 = *(const float4*)(B1 + 32 * ct + 8 * H);
    const float4 q1 = *(const float4*)(B1 + 32 * ct + 8 * H + 4);
    const float4 q2 = *(const float4*)(B1 + 32 * ct + 8 * H + 16);
    const float4 q3 = *(const float4*)(B1 + 32 * ct + 8 * H + 20);
    f32x16 binit;
    binit[0] = q0.x; binit[1] = q0.y; binit[2] = q0.z; binit[3] = q0.w;
    binit[4] = q1.x; binit[5] = q1.y; binit[6] = q1.z; binit[7] = q1.w;
    binit[8] = q2.x; binit[9] = q2.y; binit[10] = q2.z; binit[11] = q2.w;
    binit[12] = q3.x; binit[13] = q3.y; binit[14] = q3.z; binit[15] = q3.w;

    f32x16 acc1a = binit;
#pragma unroll
    for (int kk = 0; kk < 4; ++kk)
      acc1a = __builtin_amdgcn_mfma_f32_32x32x16_bf16(a1[kk], xf[0][kk], acc1a, 0, 0, 0);
    uint4 lo0, hi0;
    lo0.x = cvt_pk(fmaxf(acc1a[0], 0.f), fmaxf(acc1a[1], 0.f));
    lo0.y = cvt_pk(fmaxf(acc1a[2], 0.f), fmaxf(acc1a[3], 0.f));
    lo0.z = cvt_pk(fmaxf(acc1a[4], 0.f), fmaxf(acc1a[5], 0.f));
    lo0.w = cvt_pk(fmaxf(acc1a[6], 0.f), fmaxf(acc1a[7], 0.f));
    hi0.x = cvt_pk(fmaxf(acc1a[8], 0.f), fmaxf(acc1a[9], 0.f));
    hi0.y = cvt_pk(fmaxf(acc1a[10], 0.f), fmaxf(acc1a[11], 0.f));
    hi0.z = cvt_pk(fmaxf(acc1a[12], 0.f), fmaxf(acc1a[13], 0.f));
    hi0.w = cvt_pk(fmaxf(acc1a[14], 0.f), fmaxf(acc1a[15], 0.f));

    f32x16 acc1b = binit;
#pragma unroll
    for (int kk = 0; kk < 4; ++kk)
      acc1b = __builtin_amdgcn_mfma_f32_32x32x16_bf16(a1[kk], xf[1][kk], acc1b, 0, 0, 0);
    uint4 lo1, hi1;
    lo1.x = cvt_pk(fmaxf(acc1b[0], 0.f), fmaxf(acc1b[1], 0.f));
    lo1.y = cvt_pk(fmaxf(acc1b[2], 0.f), fmaxf(acc1b[3], 0.f));
    lo1.z = cvt_pk(fmaxf(acc1b[4], 0.f), fmaxf(acc1b[5], 0.f));
    lo1.w = cvt_pk(fmaxf(acc1b[6], 0.f), fmaxf(acc1b[7], 0.f));
    hi1.x = cvt_pk(fmaxf(acc1b[8], 0.f), fmaxf(acc1b[9], 0.f));
    hi1.y = cvt_pk(fmaxf(acc1b[10], 0.f), fmaxf(acc1b[11], 0.f));
    hi1.z = cvt_pk(fmaxf(acc1b[12], 0.f), fmaxf(acc1b[13], 0.f));
    hi1.w = cvt_pk(fmaxf(acc1b[14], 0.f), fmaxf(acc1b[15], 0.f));

    if (ct < 7) {  // prefetch next chunk's W1 frags under layer-2 MFMAs
#pragma unroll
      for (int kk = 0; kk < 4; ++kk)
        a1[kk] = *(const bf16x8*)&w1f[((ct + 1) * 4 + kk) * 512 + lane * 8];
    }

#pragma unroll
    for (int q = 0; q < 4; ++q) {
      const bf16x8 wlo = *(const bf16x8*)&w2f[(8 * ct + q) * 512 + lane * 8];
      acc2[0][q] = __builtin_amdgcn_mfma_f32_32x32x16_bf16(
          wlo, __builtin_bit_cast(bf16x8, lo0), acc2[0][q], 0, 0, 0);
      acc2[1][q] = __builtin_amdgcn_mfma_f32_32x32x16_bf16(
          wlo, __builtin_bit_cast(bf16x8, lo1), acc2[1][q], 0, 0, 0);
    }
#pragma unroll
    for (int q = 0; q < 4; ++q) {
      const bf16x8 whi = *(const bf16x8*)&w2f[(8 * ct + 4 + q) * 512 + lane * 8];
      acc2[0][q] = __builtin_amdgcn_mfma_f32_32x32x16_bf16(
          whi, __builtin_bit_cast(bf16x8, hi0), acc2[0][q], 0, 0, 0);
      acc2[1][q] = __builtin_amdgcn_mfma_f32_32x32x16_bf16(
          whi, __builtin_bit_cast(bf16x8, hi1), acc2[1][q], 0, 0, 0);
    }
  }

  // ---- layer 3: relu(h2) . W3; rows split across lane halves ----
  float part = 0.f;
#pragma unroll
  for (int n2 = 0; n2 < 4; ++n2) {
#pragma unroll
    for (int rq = 0; rq < 4; ++rq) {
      const float4 wq = *(const float4*)(W3 + 32 * n2 + 8 * rq + 4 * H);
      const float wv4[4] = {wq.x, wq.y, wq.z, wq.w};
#pragma unroll
      for (int s = 0; s < 4; ++s) {
        part += fmaxf(acc2[0][n2][4 * rq + s], 0.f) * wv4[s];
        part += fmaxf(acc2[1][n2][4 * rq + s], 0.f) * wv4[s];
      }
    }
  }
  part += __shfl_xor(part, 32, 64);  // combine row-halves (same sample)
  if (lane < 32) out[sbase + lane] = part + 2.f * B3[0];
}

extern "C" void kernel_launch(void* const* d_in, const int* in_sizes, int n_in,
                              void* d_out, int out_size, void* d_ws, size_t ws_size,
                              hipStream_t stream) {
  const int* uids = (const int*)d_in[0];
  const int* mids = (const int*)d_in[1];
  const float* EU = (const float*)d_in[2];
  const float* EM = (const float*)d_in[3];
  const float* W1 = (const float*)d_in[4];
  const float* B1 = (const float*)d_in[5];
  const float* W2 = (const float*)d_in[6];
  const float* B2 = (const float*)d_in[7];
  const float* W3 = (const float*)d_in[8];
  const float* B3 = (const float*)d_in[9];
  float* out = (float*)d_out;

  const int B = in_sizes[0];  // 65536
  const int nblk = B / 256;   // 256 blocks x 256 samples
  hipLaunchKernelGGL(movielens_mlp, dim3(nblk), dim3(512), 0, stream,
                     uids, mids, EU, EM, W1, B1, W2, B2, W3, B3, out);
}